// Round 10
// baseline (51.196 us; speedup 1.0000x reference)
//
#include <hip/hip_runtime.h>
#include <math.h>
#include <utility>

#define DIMS  16
#define BATCH 32768
#define NPAIR 136
#define NMT   5        // M-tiles of 32 (rows 0..159)
#define NKK   10       // K-steps of 16 (K = 160)
#define A_ELEMS (NKK*NMT*64*8)   // 25600 bf16, fragment-sliced
#define A_U32   (A_ELEMS/2)      // 12800

typedef short s16x8  __attribute__((ext_vector_type(8)));
typedef float f32x16 __attribute__((ext_vector_type(16)));

// ---------- compile-time combinatorics (lex = combinations_with_replacement) ----------
constexpr int pairlex(int i0, int i1){ int s=0; for(int j=0;j<i0;++j) s+=(DIMS-j); return s+(i1-i0); }
constexpr int pid_i0(int pid){ int i0=0,rem=pid; while(rem>=DIMS-i0){rem-=DIMS-i0;++i0;} return i0; }
constexpr int pid_i1(int pid){ int i0=0,rem=pid; while(rem>=DIMS-i0){rem-=DIMS-i0;++i0;} return i0+rem; }
constexpr int cnt3(int j){ return (DIMS-j)*(DIMS+1-j)/2; }
constexpr int off3(int i0){ int s=0; for(int j=0;j<i0;++j) s+=cnt3(j); return s; }
constexpr int cnt4j(int j){ return (DIMS-j)*(DIMS+1-j)*(DIMS+2-j)/6; }
constexpr int off4(int i0){ int s=0; for(int j=0;j<i0;++j) s+=cnt4j(j); return s; }
// W layout: [0]=const, [1..16]=deg1, [17..152]=deg2, [153..968]=deg3, [969..4844]=deg4
constexpr int w3rowbase(int i0){ return 1+DIMS+NPAIR+off3(i0); }
constexpr int w4base(int i0,int i1){ int s=off4(i0); for(int b=i0;b<i1;++b) s+=cnt3(b); return 1+DIMS+NPAIR+816+s; }
static_assert(pairlex(15,15)==135 && off3(DIMS)==816 && off4(DIMS)==3876, "combi");
static_assert(w4base(15,15)==4844, "wtail");

// ---------- row metadata (r3..r8-verified) ----------
struct RowMeta { short qs, qe, wb, deg; };
struct RowTab  { RowMeta m[NMT*32]; };
constexpr RowTab make_rowtab(){
    RowTab t{};
    for (int r = 0; r < NMT*32; ++r) {
        RowMeta rm{0,0,0,0};
        if (r < NPAIR) {
            int i0 = pid_i0(r), i1 = pid_i1(r);
            rm = RowMeta{ (short)pairlex(i1,i1), (short)NPAIR, (short)w4base(i0,i1), 4 };
        } else if (r < NPAIR + DIMS) {
            int i0 = r - NPAIR;
            rm = RowMeta{ (short)pairlex(i0,i0), (short)NPAIR, (short)w3rowbase(i0), 3 };
        } else if (r == 152) {
            rm = RowMeta{ 0, (short)NPAIR, (short)(1+DIMS), 2 };
        } else if (r == 153) {
            rm = RowMeta{ (short)NPAIR, (short)(NPAIR+DIMS), 1, 1 };
        }
        t.m[r] = rm;
    }
    return t;
}

// ---------- DESC: A-slot (fragment layout) -> (deg<<13 | W index); 0 => zero ----------
struct DescT { unsigned short d[A_ELEMS]; };
constexpr DescT make_desc(){
    DescT D{};
    const RowTab rt = make_rowtab();
    for (int id = 0; id < A_ELEMS; ++id) {
        const int e = id & 7, ln = (id >> 3) & 63, mtkk = id >> 9;
        const int mt = mtkk % NMT, kk = mtkk / NMT;
        const int row = mt*32 + (ln & 31);
        const int k   = kk*16 + 4*(ln >> 5) + (e & 3) + 8*(e >> 2);
        const RowMeta rm = rt.m[row];
        unsigned short v = 0;
        if (k >= rm.qs && k < rm.qe)
            v = (unsigned short)(((unsigned)rm.deg << 13) | (unsigned)(rm.wb + k - rm.qs));
        D.d[id] = v;
    }
    return D;
}
__device__ __constant__ DescT DESC = make_desc();

// ---------- helpers ----------
__device__ __forceinline__ ushort f2bf(float f){
    union { float f; unsigned u; } v{f};
    return (ushort)((v.u + 0x7FFF + ((v.u >> 16) & 1)) >> 16);   // RNE
}
__device__ __forceinline__ unsigned packbf(float a, float b){    // RNE pack of 2 bf16
    const unsigned ua = __float_as_uint(a) + 0x8000u;
    const unsigned ub = __float_as_uint(b) + 0x8000u;
    return (ua >> 16) | (ub & 0xFFFF0000u);
}

template<typename F, int... Is>
__device__ __forceinline__ void sfor_impl(F&& f, std::integer_sequence<int,Is...>){
    (f(std::integral_constant<int,Is>{}), ...);
}
template<int N, typename F>
__device__ __forceinline__ void sfor(F&& f){
    sfor_impl(static_cast<F&&>(f), std::make_integer_sequence<int,N>{});
}

// F row value (static row -> static xv indices)
template<int R>
__device__ __forceinline__ float fval(const float (&xv)[DIMS]){
    if constexpr      (R < NPAIR)        return xv[pid_i0(R)] * xv[pid_i1(R)];
    else if constexpr (R < NPAIR+DIMS)   return xv[R - NPAIR];
    else if constexpr (R < 154)          return 1.0f;
    else                                 return 0.0f;
}

// ---------- one M-tile: 10 MFMAs into ONE reused acc + in-register epilogue ----------
// af from LDS; multipliers from own bfw regs (r6/r8-verified algebra).
template<int MT>
__device__ __forceinline__ float do_mt(const ushort* __restrict__ A_sh,
                                       const unsigned (&bfw)[NKK][4], int lane)
{
    f32x16 acc = {};
    sfor<NKK>([&](auto K){ constexpr int kk = decltype(K)::value;
        union { unsigned u[4]; s16x8 v; } bu;
        bu.u[0]=bfw[kk][0]; bu.u[1]=bfw[kk][1]; bu.u[2]=bfw[kk][2]; bu.u[3]=bfw[kk][3];
        const s16x8 af = *reinterpret_cast<const s16x8*>(
            A_sh + (size_t)((kk*NMT + MT)*64 + lane)*8);
        acc = __builtin_amdgcn_mfma_f32_32x32x16_bf16(af, bu.v, acc, 0, 0, 0);
    });
    float p = 0.0f;
    sfor<16>([&](auto R){ constexpr int reg = decltype(R)::value;
        constexpr int kksel = 2*MT + (reg >> 3);
        constexpr int word  = ((reg & 3) >> 1) + 2*((reg >> 2) & 1);
        const unsigned w = bfw[kksel][word];
        const float mult = __uint_as_float((reg & 1) ? (w & 0xFFFF0000u) : (w << 16));
        p = fmaf(mult, acc[reg], p);
    });
    return p + __shfl_xor(p, 32);        // combine the two h-halves (row sets)
}

// ---------- single fused kernel: 256 blocks x 512 thr (8 waves = 4 pairs x 2 halves) ----------
// In-block A-build (DESC, verified) -> LDS; F in registers; one acc; mt-split across pair.
__global__ __launch_bounds__(512, 2)
void poly_logreg_fused(const float* __restrict__ x, const float* __restrict__ W,
                       const float* __restrict__ b, const float* __restrict__ M_raw,
                       float* __restrict__ out)
{
    __shared__ __align__(16) ushort A_sh[A_ELEMS];
    __shared__ float red[4][32];

    const int t = threadIdx.x, lane = t & 63, wv = t >> 6;
    const int pair = wv >> 1, half = wv & 1;
    const int col = lane & 31;
    const bool hs = lane >= 32;
    const size_t s0 = (size_t)blockIdx.x * 128 + pair * 32;

    // ---- x loads (issued first) ----
    const float4* xp = reinterpret_cast<const float4*>(x + (s0 + col)*DIMS);
    const float4 xa = xp[0], xb = xp[1], xc = xp[2], xd = xp[3];

    // ---- degree gates (uniform) ----
    const float M  = 3.0f/(1.0f+__expf(-M_raw[0])) + 1.0f;
    const float g1 = 1.0f/(1.0f+__expf(-10.0f*(M-0.5f)));
    const float g2 = 1.0f/(1.0f+__expf(-10.0f*(M-1.5f)));
    const float g3 = 1.0f/(1.0f+__expf(-10.0f*(M-2.5f)));
    const float g4 = 1.0f/(1.0f+__expf(-10.0f*(M-3.5f)));

    // ---- in-block A-build: 25 coalesced DESC u32 + L1-resident W gathers -> LDS ----
    {
        const unsigned* D32 = reinterpret_cast<const unsigned*>(DESC.d);
        unsigned* A32 = reinterpret_cast<unsigned*>(A_sh);
        #pragma unroll 5
        for (int i = 0; i < A_U32/512; ++i) {
            const int j = i*512 + t;
            const unsigned d  = D32[j];
            const unsigned d0 = d & 0xFFFFu, d1 = d >> 16;
            const int deg0 = d0 >> 13, deg1 = d1 >> 13;
            const float gv0 = deg0==4?g4 : deg0==3?g3 : deg0==2?g2 : deg0==1?g1 : 0.0f;
            const float gv1 = deg1==4?g4 : deg1==3?g3 : deg1==2?g2 : deg1==1?g1 : 0.0f;
            A32[j] = packbf(gv0 * W[d0 & 0x1FFF], gv1 * W[d1 & 0x1FFF]);
        }
    }

    // ---- F-build into packed B-frag registers (r6/r8-verified) ----
    float xv[DIMS];
    xv[0]=xa.x; xv[1]=xa.y; xv[2]=xa.z; xv[3]=xa.w;
    xv[4]=xb.x; xv[5]=xb.y; xv[6]=xb.z; xv[7]=xb.w;
    xv[8]=xc.x; xv[9]=xc.y; xv[10]=xc.z; xv[11]=xc.w;
    xv[12]=xd.x; xv[13]=xd.y; xv[14]=xd.z; xv[15]=xd.w;

    unsigned bfw[NKK][4];
    sfor<NKK>([&](auto K){ constexpr int kk = decltype(K)::value;
        sfor<4>([&](auto J){ constexpr int j = decltype(J)::value;
            constexpr int e0 = 2*j, e1 = 2*j + 1;
            constexpr int r0a = 16*kk + (e0 & 3) + 8*(e0 >> 2);
            constexpr int r0b = 16*kk + (e1 & 3) + 8*(e1 >> 2);
            const float va = hs ? fval<r0a+4>(xv) : fval<r0a>(xv);
            const float vb = hs ? fval<r0b+4>(xv) : fval<r0b>(xv);
            bfw[kk][j] = packbf(va, vb);
        });
    });
    __syncthreads();

    // ---- GEMM: waveA (half 0) -> mt 0,1,2 ; waveB (half 1) -> mt 3,4 ----
    if (half) {
        const float ptot = do_mt<3>(A_sh, bfw, lane) + do_mt<4>(A_sh, bfw, lane);
        if (lane < 32) red[pair][lane] = ptot;
    }
    __syncthreads();
    if (!half) {
        const float ptot = do_mt<0>(A_sh, bfw, lane) + do_mt<1>(A_sh, bfw, lane)
                         + do_mt<2>(A_sh, bfw, lane);
        if (lane < 32) {
            const float logit = ptot + red[pair][lane] + W[0] + b[0];
            out[s0 + col] = 1.0f/(1.0f+__expf(-logit));
        }
    }
}

extern "C" void kernel_launch(void* const* d_in, const int* in_sizes, int n_in,
                              void* d_out, int out_size, void* d_ws, size_t ws_size,
                              hipStream_t stream)
{
    const float* x     = (const float*)d_in[0];
    const float* W     = (const float*)d_in[1];
    const float* b     = (const float*)d_in[2];
    const float* M_raw = (const float*)d_in[3];
    float* out = (float*)d_out;

    poly_logreg_fused<<<BATCH/128, 512, 0, stream>>>(x, W, b, M_raw, out);
}